// Round 15
// baseline (174.660 us; speedup 1.0000x reference)
//
#include <hip/hip_runtime.h>
#include <hip/hip_bf16.h>

#define BB 32
#define NN 1024
#define QQ 64
#define HH 768

typedef __attribute__((ext_vector_type(8))) short short8;
typedef __attribute__((ext_vector_type(4))) float f32x4;

#define GLOAD_LDS16(gp, lp) \
  __builtin_amdgcn_global_load_lds((const __attribute__((address_space(1))) unsigned int*)(gp), \
                                   (__attribute__((address_space(3))) unsigned int*)(lp), 16, 0, 0)

__device__ __forceinline__ unsigned short f2b(float f) {
  unsigned int u = __float_as_uint(f);
  unsigned int r = u + 0x7fffu + ((u >> 16) & 1u);
  return (unsigned short)(r >> 16);
}

// K0: one block per (b, hc): qc tile -> LDS once; emit qwB (folded, swizzled),
// qcT (transposed, swizzled), sq partials. (R11 structure, unchanged)
__global__ __launch_bounds__(256) void k_prep(
    const float* __restrict__ qc, const float* __restrict__ w,
    unsigned short* __restrict__ qwB, unsigned short* __restrict__ qcT,
    float* __restrict__ sq_part) {
  __shared__ float qcL[128][66];

  const int tid = threadIdx.x;
  const int bid = blockIdx.x;      // b*6 + hc
  const int b = bid / 6, hc = bid % 6;
  const float* qcB = qc + (size_t)(b * 64) * HH + hc * 128;

#pragma unroll
  for (int i = 0; i < 8; ++i) {
    int u = i * 256 + tid;
    int q = u >> 5, c4 = u & 31;
    float4 v = *(const float4*)(qcB + (size_t)q * HH + c4 * 4);
    qcL[c4 * 4 + 0][q] = v.x;
    qcL[c4 * 4 + 1][q] = v.y;
    qcL[c4 * 4 + 2][q] = v.z;
    qcL[c4 * 4 + 3][q] = v.w;
  }
  __syncthreads();

  {
    char* dst = (char*)qwB + ((size_t)bid << 14);
#pragma unroll
    for (int i = 0; i < 4; ++i) {
      int p = i * 256 + tid;
      int q = p >> 4, uu = p & 15;
      int hg = hc * 128 + uu * 8;
      short8 v;
#pragma unroll
      for (int j = 0; j < 8; ++j)
        v[j] = (short)f2b(qcL[uu * 8 + j][q] * w[2 * HH + hg + j] + w[hg + j]);
      *(short8*)(dst + ((size_t)(q * 16 + (uu ^ (q & 7)))) * 16) = v;
    }
  }
  {
    char* dst = (char*)qcT + ((size_t)bid << 14);
#pragma unroll
    for (int i = 0; i < 4; ++i) {
      int p = i * 256 + tid;
      int r = p >> 3, x = p & 7;
      int xu = x ^ (r & 7);
      short8 v;
#pragma unroll
      for (int j = 0; j < 8; ++j) v[j] = (short)f2b(qcL[r][xu * 8 + j]);
      *(short8*)(dst + (size_t)p * 16) = v;
    }
  }
  {
    int q = tid >> 2, qt = tid & 3;
    float s = 0.f;
#pragma unroll
    for (int k = 0; k < 32; ++k)
      s += qcL[qt * 32 + k][q] * w[HH + hc * 128 + qt * 32 + k];
    s += __shfl_xor(s, 1);
    s += __shfl_xor(s, 2);
    if (qt == 0) sq_part[bid * 64 + q] = s;
  }
}

// K1: split-K GEMM1. Block (b, tile, kh): 64x64 sim partial over 384 K-cols,
// 3 staged phases, dbuf (32 KB LDS -> 4 blocks/CU). Grid 1024, XCD swizzle.
__global__ __launch_bounds__(256) void k_mm(
    const float* __restrict__ nc, const unsigned short* __restrict__ qwB,
    float* __restrict__ simh)
{
  __shared__ __align__(16) char bbuf[2][16384];

  const int tid = threadIdx.x;
  const int wv_ = tid >> 6, l = tid & 63;
  const int l15 = l & 15, lg = l >> 4;
  const int lb = (blockIdx.x & 7) * 128 + (blockIdx.x >> 3);  // XCD-contig
  const int b = lb >> 5, tile = (lb >> 1) & 15, kh = lb & 1;
  const int row0 = tile * 64;

  const float* ncB = nc + (size_t)(b * NN + row0) * HH;
  const char* qwb = (const char*)qwB + (size_t)b * 98304 + (size_t)kh * 49152;
  const float* aBase = ncB + (wv_ * 16 + l15) * HH + kh * 384 + lg * 8;

  // prologue: A(0) first (so B' stays newer), then B'(0)
  float4 fr[2][8];
#pragma unroll
  for (int ks = 0; ks < 4; ++ks) {
    fr[0][ks * 2]     = *(const float4*)(aBase + ks * 32);
    fr[0][ks * 2 + 1] = *(const float4*)(aBase + ks * 32 + 4);
  }
  {
    const char* gsrc = qwb + wv_ * 4096 + l * 16;
#pragma unroll
    for (int i = 0; i < 4; ++i)
      GLOAD_LDS16(gsrc + i * 1024, &bbuf[0][wv_ * 4096 + i * 1024]);
  }

  f32x4 acc[4] = {};
#pragma unroll
  for (int kc = 0; kc < 3; ++kc) {
    short8 af[4];
#pragma unroll
    for (int ks = 0; ks < 4; ++ks) {
      float4 f0 = fr[kc & 1][ks * 2], f1 = fr[kc & 1][ks * 2 + 1];
      short8 v;
      v[0] = (short)f2b(f0.x); v[1] = (short)f2b(f0.y);
      v[2] = (short)f2b(f0.z); v[3] = (short)f2b(f0.w);
      v[4] = (short)f2b(f1.x); v[5] = (short)f2b(f1.y);
      v[6] = (short)f2b(f1.z); v[7] = (short)f2b(f1.w);
      af[ks] = v;
    }
    if (kc < 2) {
      // A(kc+1) first, then B'(kc+1) into the other buffer
#pragma unroll
      for (int ks = 0; ks < 4; ++ks) {
        fr[(kc + 1) & 1][ks * 2]     = *(const float4*)(aBase + (kc + 1) * 128 + ks * 32);
        fr[(kc + 1) & 1][ks * 2 + 1] = *(const float4*)(aBase + (kc + 1) * 128 + ks * 32 + 4);
      }
      const char* gsrc = qwb + (kc + 1) * 16384 + wv_ * 4096 + l * 16;
#pragma unroll
      for (int i = 0; i < 4; ++i)
        GLOAD_LDS16(gsrc + i * 1024, &bbuf[(kc + 1) & 1][wv_ * 4096 + i * 1024]);
      asm volatile("s_waitcnt vmcnt(12)" ::: "memory");  // drain B'(kc); 12 prefetches live
    } else {
      asm volatile("s_waitcnt vmcnt(0)" ::: "memory");
    }
    __builtin_amdgcn_s_barrier();
    __builtin_amdgcn_sched_barrier(0);
#pragma unroll
    for (int ks = 0; ks < 4; ++ks) {
      int kbyte = ks * 64 + lg * 16;
#pragma unroll
      for (int nt = 0; nt < 4; ++nt) {
        int brow = nt * 16 + l15;
        short8 bf = *(short8*)(&bbuf[kc & 1][0] + brow * 256 + (kbyte ^ ((l & 7) << 4)));
        acc[nt] = __builtin_amdgcn_mfma_f32_16x16x32_bf16(af[ks], bf, acc[nt], 0, 0, 0);
      }
    }
    __builtin_amdgcn_sched_barrier(0);
    if (kc == 0) __builtin_amdgcn_s_barrier();  // protect bbuf[0] before kc=1 restage
  }

  // write sim partial (L2-resident: 2 MB/XCD)
  float* sh = simh + ((size_t)((b * 16 + tile) * 2 + kh)) * 4096;
#pragma unroll
  for (int nt = 0; nt < 4; ++nt)
#pragma unroll
    for (int j = 0; j < 4; ++j)
      sh[(wv_ * 16 + lg * 4 + j) * 64 + nt * 16 + l15] = acc[nt][j];
}

// K2: combine K-halves + bias + softmax -> probs, per-tile q2n partials + mtse.
// Grid 512, XCD swizzle consistent with k_mm.
__global__ __launch_bounds__(256) void k_soft(
    const float* __restrict__ nc, const float* __restrict__ simh,
    const float* __restrict__ sq_part, float* __restrict__ partial,
    float* __restrict__ mtse, unsigned short* __restrict__ probs)
{
  __shared__ float rowmF[64];
  __shared__ float wvF[64];
  __shared__ float pW[4][768];

  const int tid = threadIdx.x;
  const int wv_ = tid >> 6, l = tid & 63;
  const int l15 = l & 15, lg = l >> 4;
  const int lb = (blockIdx.x & 7) * 64 + (blockIdx.x >> 3);
  const int b = lb >> 4, tile = lb & 15;
  const int row0 = tile * 64;

  const float* ncB = nc + (size_t)(b * NN + row0) * HH;
  const float* sh0 = simh + ((size_t)((b * 16 + tile) * 2)) * 4096;
  const float* sh1 = sh0 + 4096;

  f32x4 acc[4];
  float sqv[4];
#pragma unroll
  for (int nt = 0; nt < 4; ++nt) {
    float s = 0.f;
#pragma unroll
    for (int i = 0; i < 6; ++i) s += sq_part[(b * 6 + i) * 64 + nt * 16 + l15];
    sqv[nt] = s;
#pragma unroll
    for (int j = 0; j < 4; ++j) {
      int idx = (wv_ * 16 + lg * 4 + j) * 64 + nt * 16 + l15;
      acc[nt][j] = sh0[idx] + sh1[idx];
    }
  }

  unsigned short* pT = probs + (size_t)(b * 16 + tile) * (QQ * QQ);
#pragma unroll
  for (int j = 0; j < 4; ++j) {
    float mm = -1e30f;
#pragma unroll
    for (int nt = 0; nt < 4; ++nt) { acc[nt][j] += sqv[nt]; mm = fmaxf(mm, acc[nt][j]); }
    mm = fmaxf(mm, __shfl_xor(mm, 1));
    mm = fmaxf(mm, __shfl_xor(mm, 2));
    mm = fmaxf(mm, __shfl_xor(mm, 4));
    mm = fmaxf(mm, __shfl_xor(mm, 8));
    float ss = 0.f;
#pragma unroll
    for (int nt = 0; nt < 4; ++nt) { float p = __expf(acc[nt][j] - mm); acc[nt][j] = p; ss += p; }
    ss += __shfl_xor(ss, 1); ss += __shfl_xor(ss, 2);
    ss += __shfl_xor(ss, 4); ss += __shfl_xor(ss, 8);
    float inv = 1.0f / ss;
    int r = wv_ * 16 + lg * 4 + j;
#pragma unroll
    for (int nt = 0; nt < 4; ++nt)
      pT[r * 64 + nt * 16 + l15] = f2b(acc[nt][j] * inv);
    if (l15 == 0) rowmF[r] = mm;
  }
  __syncthreads();

  float m_t = -1e30f;
#pragma unroll
  for (int i = 0; i < 16; ++i) {
    f32x4 v = ((f32x4*)rowmF)[i];
    m_t = fmaxf(m_t, fmaxf(fmaxf(v[0], v[1]), fmaxf(v[2], v[3])));
  }
  if (tid < 64) wvF[tid] = __expf(rowmF[tid] - m_t);
  __syncthreads();
  {
    float sv = wvF[l];
#pragma unroll
    for (int m = 1; m < 64; m <<= 1) sv += __shfl_xor(sv, m);
    if (tid == 0) {
      mtse[(b * 16 + tile) * 2] = m_t;
      mtse[(b * 16 + tile) * 2 + 1] = sv;
    }
  }
  {
    float a[12];
#pragma unroll
    for (int j = 0; j < 12; ++j) a[j] = 0.f;
    for (int n0 = 0; n0 < 16; ++n0) {
      int n = wv_ * 16 + n0;
      float wvv = wvF[n];
      const float* pr = ncB + (size_t)n * HH;
#pragma unroll
      for (int j = 0; j < 12; ++j) a[j] += wvv * pr[l + j * 64];
    }
#pragma unroll
    for (int j = 0; j < 12; ++j) pW[wv_][l + j * 64] = a[j];
  }
  __syncthreads();
  {
    float* pp = partial + (size_t)(b * 16 + tile) * HH + tid;
    pp[0]   = pW[0][tid]       + pW[1][tid]       + pW[2][tid]       + pW[3][tid];
    pp[256] = pW[0][tid + 256] + pW[1][tid + 256] + pW[2][tid + 256] + pW[3][tid + 256];
    pp[512] = pW[0][tid + 512] + pW[1][tid + 512] + pW[2][tid + 512] + pW[3][tid + 512];
  }
}

// K3: GEMM2 (swapped: D[h][n]) + q2n combine (folded) + all four output chunks.
// Grid 3072 = 8*384, XCD swizzle consistent. (R13 structure, unchanged)
__global__ __launch_bounds__(256) void k_out(
    const float* __restrict__ nc, const unsigned short* __restrict__ qcT,
    const unsigned short* __restrict__ probs, const float* __restrict__ partial,
    const float* __restrict__ mtse, float* __restrict__ out)
{
  __shared__ __align__(16) char smem[16384];
  __shared__ float q2nL[128];

  const int tid = threadIdx.x;
  const int wv_ = tid >> 6, l = tid & 63;
  const int l15 = l & 15, lg = l >> 4;
  const int lb = (blockIdx.x & 7) * 384 + (blockIdx.x >> 3);
  const int hc = lb % 6;
  const int bt = lb / 6;
  const int b = bt >> 4, tile = bt & 15;
  const int row0 = tile * 64;

  {
    const char* src = (const char*)qcT + ((size_t)(b * 6 + hc) << 14) + wv_ * 4096 + l * 16;
#pragma unroll
    for (int i = 0; i < 4; ++i)
      GLOAD_LDS16(src + i * 1024, &smem[wv_ * 4096 + i * 1024]);
  }

  if (tid < 128) {
    float M = -1e30f, mt[16], se[16];
#pragma unroll
    for (int i = 0; i < 16; ++i) {
      mt[i] = mtse[(b * 16 + i) * 2];
      se[i] = mtse[(b * 16 + i) * 2 + 1];
      M = fmaxf(M, mt[i]);
    }
    float denom = 0.f;
#pragma unroll
    for (int i = 0; i < 16; ++i) { mt[i] = __expf(mt[i] - M); denom += mt[i] * se[i]; }
    float inv = 1.0f / denom;
    float a = 0.f;
#pragma unroll
    for (int i = 0; i < 16; ++i)
      a += mt[i] * partial[(size_t)(b * 16 + i) * HH + hc * 128 + tid];
    q2nL[tid] = a * inv;
  }

  const unsigned short* pT = probs + (size_t)bt * (QQ * QQ);
  short8 a2_0 = *(const short8*)((const char*)pT + (wv_ * 16 + l15) * 128 + lg * 16);
  short8 a2_1 = *(const short8*)((const char*)pT + (wv_ * 16 + l15) * 128 + 64 + lg * 16);

  asm volatile("s_waitcnt vmcnt(0)" ::: "memory");
  __syncthreads();

  const int n = wv_ * 16 + l15;
  const float* ncrow = nc + (size_t)(b * NN + row0 + n) * HH;
  float* orow = out + (size_t)(b * NN + row0 + n) * 3072;

#pragma unroll
  for (int hg = 0; hg < 8; ++hg) {
    f32x4 c2 = {};
#pragma unroll
    for (int ks2 = 0; ks2 < 2; ++ks2) {
      int hrow = hg * 16 + l15;
      int kbyte = ks2 * 64 + lg * 16;
      short8 hf = *(short8*)(&smem[0] + hrow * 128 + (kbyte ^ ((l & 7) << 4)));
      c2 = __builtin_amdgcn_mfma_f32_16x16x32_bf16(hf, ks2 ? a2_1 : a2_0, c2, 0, 0, 0);
    }
    int hl = hg * 16 + lg * 4;
    int hbase = hc * 128 + hl;
    f32x4 ncv = *(const f32x4*)(ncrow + hbase);
    f32x4 qv  = *(const f32x4*)(&q2nL[hl]);
    *(f32x4*)(orow + hbase)          = ncv;
    *(f32x4*)(orow + HH + hbase)     = c2;
    *(f32x4*)(orow + 2 * HH + hbase) = ncv * c2;
    *(f32x4*)(orow + 2304 + hbase)   = ncv * qv;
  }
}

extern "C" void kernel_launch(void* const* d_in, const int* in_sizes, int n_in,
                              void* d_out, int out_size, void* d_ws, size_t ws_size,
                              hipStream_t stream) {
  (void)in_sizes; (void)n_in; (void)out_size; (void)ws_size;
  const float* nc = (const float*)d_in[0];
  const float* qc = (const float*)d_in[1];
  const float* w  = (const float*)d_in[3];
  float* out = (float*)d_out;
  char* ws = (char*)d_ws;
  unsigned short* qwB = (unsigned short*)(ws);                 // 3,145,728 B (pre-swizzled)
  unsigned short* qcT = (unsigned short*)(ws + 3145728);       // 3,145,728 B (pre-swizzled)
  float* sq_part = (float*)(ws + 6291456);                     // 49,152 B
  float* partial = (float*)(ws + 6340608);                     // 1,572,864 B
  float* mtse    = (float*)(ws + 7913472);                     // 4 KB
  unsigned short* probs = (unsigned short*)(ws + 7917568);     // 4,194,304 B
  float* simh    = (float*)(ws + 12111872);                    // 16,777,216 B

  k_prep<<<192, 256, 0, stream>>>(qc, w, qwB, qcT, sq_part);
  k_mm<<<1024, 256, 0, stream>>>(nc, qwB, simh);
  k_soft<<<512, 256, 0, stream>>>(nc, simh, sq_part, partial, mtse, probs);
  k_out<<<3072, 256, 0, stream>>>(nc, qcT, probs, partial, mtse, out);
}

// Round 16
// 153.611 us; speedup vs baseline: 1.1370x; 1.1370x over previous
//
#include <hip/hip_runtime.h>
#include <hip/hip_bf16.h>

#define BB 32
#define NN 1024
#define QQ 64
#define HH 768

typedef __attribute__((ext_vector_type(8))) short short8;
typedef __attribute__((ext_vector_type(4))) float f32x4;

#define GLOAD_LDS16(gp, lp) \
  __builtin_amdgcn_global_load_lds((const __attribute__((address_space(1))) unsigned int*)(gp), \
                                   (__attribute__((address_space(3))) unsigned int*)(lp), 16, 0, 0)

__device__ __forceinline__ unsigned short f2b(float f) {
  unsigned int u = __float_as_uint(f);
  unsigned int r = u + 0x7fffu + ((u >> 16) & 1u);
  return (unsigned short)(r >> 16);
}

// packed RNE f32x2 -> bf16x2 (compiler emits v_cvt_pk_bf16_f32); lo = a, hi = b
__device__ __forceinline__ unsigned int pk2(float a, float b) {
  __hip_bfloat162 t = __float22bfloat162_rn(make_float2(a, b));
  union { __hip_bfloat162 h; unsigned int u; } c;
  c.h = t;
  return c.u;
}

__device__ __forceinline__ short8 cvt8(float4 f0, float4 f1) {
  union { short8 s; unsigned int u[4]; } o;
  o.u[0] = pk2(f0.x, f0.y);
  o.u[1] = pk2(f0.z, f0.w);
  o.u[2] = pk2(f1.x, f1.y);
  o.u[3] = pk2(f1.z, f1.w);
  return o.s;
}

// K0: one block per (b, hc): qc tile -> LDS once; emit qwB (folded, swizzled),
// qcT (transposed, swizzled), sq partials.
__global__ __launch_bounds__(256) void k_prep(
    const float* __restrict__ qc, const float* __restrict__ w,
    unsigned short* __restrict__ qwB, unsigned short* __restrict__ qcT,
    float* __restrict__ sq_part) {
  __shared__ float qcL[128][66];

  const int tid = threadIdx.x;
  const int bid = blockIdx.x;      // b*6 + hc
  const int b = bid / 6, hc = bid % 6;
  const float* qcB = qc + (size_t)(b * 64) * HH + hc * 128;

#pragma unroll
  for (int i = 0; i < 8; ++i) {
    int u = i * 256 + tid;
    int q = u >> 5, c4 = u & 31;
    float4 v = *(const float4*)(qcB + (size_t)q * HH + c4 * 4);
    qcL[c4 * 4 + 0][q] = v.x;
    qcL[c4 * 4 + 1][q] = v.y;
    qcL[c4 * 4 + 2][q] = v.z;
    qcL[c4 * 4 + 3][q] = v.w;
  }
  __syncthreads();

  {
    char* dst = (char*)qwB + ((size_t)bid << 14);
#pragma unroll
    for (int i = 0; i < 4; ++i) {
      int p = i * 256 + tid;
      int q = p >> 4, uu = p & 15;
      int hg = hc * 128 + uu * 8;
      float e[8];
#pragma unroll
      for (int j = 0; j < 8; ++j)
        e[j] = qcL[uu * 8 + j][q] * w[2 * HH + hg + j] + w[hg + j];
      union { short8 s; unsigned int u4[4]; } o;
      o.u4[0] = pk2(e[0], e[1]); o.u4[1] = pk2(e[2], e[3]);
      o.u4[2] = pk2(e[4], e[5]); o.u4[3] = pk2(e[6], e[7]);
      *(short8*)(dst + ((size_t)(q * 16 + (uu ^ (q & 7)))) * 16) = o.s;
    }
  }
  {
    char* dst = (char*)qcT + ((size_t)bid << 14);
#pragma unroll
    for (int i = 0; i < 4; ++i) {
      int p = i * 256 + tid;
      int r = p >> 3, x = p & 7;
      int xu = x ^ (r & 7);
      union { short8 s; unsigned int u4[4]; } o;
#pragma unroll
      for (int j = 0; j < 4; ++j)
        o.u4[j] = pk2(qcL[r][xu * 8 + j * 2], qcL[r][xu * 8 + j * 2 + 1]);
      *(short8*)(dst + (size_t)p * 16) = o.s;
    }
  }
  {
    int q = tid >> 2, qt = tid & 3;
    float s = 0.f;
#pragma unroll
    for (int k = 0; k < 32; ++k)
      s += qcL[qt * 32 + k][q] * w[HH + hc * 128 + qt * 32 + k];
    s += __shfl_xor(s, 1);
    s += __shfl_xor(s, 2);
    if (qt == 0) sq_part[bid * 64 + q] = s;
  }
}

// K1: GEMM1 triple-buffered B' (1-ahead) + 1-deep A register prefetch +
// single barrier per phase + XCD swizzle + wave-parallel partials. Grid 512.
__global__ __launch_bounds__(256) void k_sim(
    const float* __restrict__ nc, const unsigned short* __restrict__ qwB,
    const float* __restrict__ sq_part, float* __restrict__ partial,
    float* __restrict__ mtse, unsigned short* __restrict__ probs)
{
  __shared__ __align__(16) char bbuf[3][16384];
  __shared__ float rowmF[64];
  __shared__ float wvF[64];
  __shared__ float pW[4][768];

  const int tid = threadIdx.x;
  const int wv_ = tid >> 6, l = tid & 63;
  const int l15 = l & 15, lg = l >> 4;
  // XCD-aware swizzle: all 16 tiles of a batch co-run on one XCD (512 = 8*64)
  const int lb = (blockIdx.x & 7) * 64 + (blockIdx.x >> 3);
  const int b = lb >> 4, tile = lb & 15;
  const int row0 = tile * 64;

  const float* ncB = nc + (size_t)(b * NN + row0) * HH;
  const char* qwb = (const char*)qwB + (size_t)b * 98304;   // 6*16384
  const float* aBase = ncB + (wv_ * 16 + l15) * HH + lg * 8;

  // ---- prologue: B'(0) -> buf0, A(0) -> fr[0] ----
  {
    const char* gsrc = qwb + wv_ * 4096 + l * 16;
#pragma unroll
    for (int i = 0; i < 4; ++i)
      GLOAD_LDS16(gsrc + i * 1024, &bbuf[0][wv_ * 4096 + i * 1024]);
  }
  float4 fr[2][8];
#pragma unroll
  for (int ks = 0; ks < 4; ++ks) {
    fr[0][ks * 2]     = *(const float4*)(aBase + ks * 32);
    fr[0][ks * 2 + 1] = *(const float4*)(aBase + ks * 32 + 4);
  }

  f32x4 acc[4] = {};
#pragma unroll
  for (int kc = 0; kc < 6; ++kc) {
    short8 af[4];
#pragma unroll
    for (int ks = 0; ks < 4; ++ks)
      af[ks] = cvt8(fr[kc & 1][ks * 2], fr[kc & 1][ks * 2 + 1]);
    if (kc < 5) {
      // issue next A (8 loads) + next B' (4 gload_lds) = 12 newest vmem ops
#pragma unroll
      for (int ks = 0; ks < 4; ++ks) {
        fr[(kc + 1) & 1][ks * 2]     = *(const float4*)(aBase + (kc + 1) * 128 + ks * 32);
        fr[(kc + 1) & 1][ks * 2 + 1] = *(const float4*)(aBase + (kc + 1) * 128 + ks * 32 + 4);
      }
      const char* gsrc = qwb + (kc + 1) * 16384 + wv_ * 4096 + l * 16;
#pragma unroll
      for (int i = 0; i < 4; ++i)
        GLOAD_LDS16(gsrc + i * 1024, &bbuf[(kc + 1) % 3][wv_ * 4096 + i * 1024]);
      asm volatile("s_waitcnt vmcnt(12)" ::: "memory");  // drains B'(kc) writes (older)
    } else {
      asm volatile("s_waitcnt vmcnt(0)" ::: "memory");
    }
    __builtin_amdgcn_s_barrier();          // single barrier per phase (3-buf safe)
    __builtin_amdgcn_sched_barrier(0);
#pragma unroll
    for (int ks = 0; ks < 4; ++ks) {
      int kbyte = ks * 64 + lg * 16;
#pragma unroll
      for (int nt = 0; nt < 4; ++nt) {
        int brow = nt * 16 + l15;
        short8 bf = *(short8*)(&bbuf[kc % 3][0] + brow * 256 + (kbyte ^ ((l & 7) << 4)));
        acc[nt] = __builtin_amdgcn_mfma_f32_16x16x32_bf16(af[ks], bf, acc[nt], 0, 0, 0);
      }
    }
    __builtin_amdgcn_sched_barrier(0);
  }
  __syncthreads();   // before reusing softmax LDS

  // ---- softmax over q; D layout: row n = wv_*16+lg*4+j, col q = nt*16+l15 ----
  unsigned short* pT = probs + (size_t)(b * 16 + tile) * (QQ * QQ);
  float sqv[4];
#pragma unroll
  for (int nt = 0; nt < 4; ++nt) {
    float s = 0.f;
#pragma unroll
    for (int i = 0; i < 6; ++i) s += sq_part[(b * 6 + i) * 64 + nt * 16 + l15];
    sqv[nt] = s;
  }
#pragma unroll
  for (int j = 0; j < 4; ++j) {
    float mm = -1e30f;
#pragma unroll
    for (int nt = 0; nt < 4; ++nt) { acc[nt][j] += sqv[nt]; mm = fmaxf(mm, acc[nt][j]); }
    mm = fmaxf(mm, __shfl_xor(mm, 1));
    mm = fmaxf(mm, __shfl_xor(mm, 2));
    mm = fmaxf(mm, __shfl_xor(mm, 4));
    mm = fmaxf(mm, __shfl_xor(mm, 8));
    float ss = 0.f;
#pragma unroll
    for (int nt = 0; nt < 4; ++nt) { float p = __expf(acc[nt][j] - mm); acc[nt][j] = p; ss += p; }
    ss += __shfl_xor(ss, 1); ss += __shfl_xor(ss, 2);
    ss += __shfl_xor(ss, 4); ss += __shfl_xor(ss, 8);
    float inv = 1.0f / ss;
    int r = wv_ * 16 + lg * 4 + j;
#pragma unroll
    for (int nt = 0; nt < 4; ++nt)
      pT[r * 64 + nt * 16 + l15] = f2b(acc[nt][j] * inv);
    if (l15 == 0) rowmF[r] = mm;
  }
  __syncthreads();

  // ---- per-tile q2n partials: wave-parallel, float4 loads (3/row/lane) ----
  float m_t = -1e30f;
#pragma unroll
  for (int i = 0; i < 16; ++i) {
    f32x4 v = ((f32x4*)rowmF)[i];
    m_t = fmaxf(m_t, fmaxf(fmaxf(v[0], v[1]), fmaxf(v[2], v[3])));
  }
  if (tid < 64) wvF[tid] = __expf(rowmF[tid] - m_t);
  __syncthreads();
  {
    float sv = wvF[l];
#pragma unroll
    for (int m = 1; m < 64; m <<= 1) sv += __shfl_xor(sv, m);
    if (tid == 0) {
      mtse[(b * 16 + tile) * 2] = m_t;
      mtse[(b * 16 + tile) * 2 + 1] = sv;
    }
  }
  {
    f32x4 a3[3] = {};
    for (int n0 = 0; n0 < 16; ++n0) {
      int n = wv_ * 16 + n0;
      float wvv = wvF[n];
      const float* pr = ncB + (size_t)n * HH;
#pragma unroll
      for (int j = 0; j < 3; ++j) {
        f32x4 v = *(const f32x4*)(pr + j * 256 + l * 4);
        a3[j] += v * wvv;
      }
    }
#pragma unroll
    for (int j = 0; j < 3; ++j)
      *(f32x4*)(&pW[wv_][j * 256 + l * 4]) = a3[j];
  }
  __syncthreads();
  {
    float* pp = partial + (size_t)(b * 16 + tile) * HH + tid;
    pp[0]   = pW[0][tid]       + pW[1][tid]       + pW[2][tid]       + pW[3][tid];
    pp[256] = pW[0][tid + 256] + pW[1][tid + 256] + pW[2][tid + 256] + pW[3][tid + 256];
    pp[512] = pW[0][tid + 512] + pW[1][tid + 512] + pW[2][tid + 512] + pW[3][tid + 512];
  }
}

// K2: GEMM2 (swapped: D[h][n]) + q2n combine (folded) + all four output chunks.
// Grid 3072 = 8*384, XCD swizzle consistent with k_sim.
__global__ __launch_bounds__(256) void k_out(
    const float* __restrict__ nc, const unsigned short* __restrict__ qcT,
    const unsigned short* __restrict__ probs, const float* __restrict__ partial,
    const float* __restrict__ mtse, float* __restrict__ out)
{
  __shared__ __align__(16) char smem[16384];   // qcT chunk [128 h][8 units], pre-swizzled
  __shared__ float q2nL[128];

  const int tid = threadIdx.x;
  const int wv_ = tid >> 6, l = tid & 63;
  const int l15 = l & 15, lg = l >> 4;
  const int lb = (blockIdx.x & 7) * 384 + (blockIdx.x >> 3);
  const int hc = lb % 6;
  const int bt = lb / 6;               // b*16 + tile
  const int b = bt >> 4, tile = bt & 15;
  const int row0 = tile * 64;

  {
    const char* src = (const char*)qcT + ((size_t)(b * 6 + hc) << 14) + wv_ * 4096 + l * 16;
#pragma unroll
    for (int i = 0; i < 4; ++i)
      GLOAD_LDS16(src + i * 1024, &smem[wv_ * 4096 + i * 1024]);
  }

  if (tid < 128) {
    float M = -1e30f, mt[16], se[16];
#pragma unroll
    for (int i = 0; i < 16; ++i) {
      mt[i] = mtse[(b * 16 + i) * 2];
      se[i] = mtse[(b * 16 + i) * 2 + 1];
      M = fmaxf(M, mt[i]);
    }
    float denom = 0.f;
#pragma unroll
    for (int i = 0; i < 16; ++i) { mt[i] = __expf(mt[i] - M); denom += mt[i] * se[i]; }
    float inv = 1.0f / denom;
    float a = 0.f;
#pragma unroll
    for (int i = 0; i < 16; ++i)
      a += mt[i] * partial[(size_t)(b * 16 + i) * HH + hc * 128 + tid];
    q2nL[tid] = a * inv;
  }

  const unsigned short* pT = probs + (size_t)bt * (QQ * QQ);
  short8 a2_0 = *(const short8*)((const char*)pT + (wv_ * 16 + l15) * 128 + lg * 16);
  short8 a2_1 = *(const short8*)((const char*)pT + (wv_ * 16 + l15) * 128 + 64 + lg * 16);

  asm volatile("s_waitcnt vmcnt(0)" ::: "memory");
  __syncthreads();

  const int n = wv_ * 16 + l15;
  const float* ncrow = nc + (size_t)(b * NN + row0 + n) * HH;
  float* orow = out + (size_t)(b * NN + row0 + n) * 3072;

#pragma unroll
  for (int hg = 0; hg < 8; ++hg) {
    f32x4 c2 = {};
#pragma unroll
    for (int ks2 = 0; ks2 < 2; ++ks2) {
      int hrow = hg * 16 + l15;
      int kbyte = ks2 * 64 + lg * 16;
      short8 hf = *(short8*)(&smem[0] + hrow * 128 + (kbyte ^ ((l & 7) << 4)));
      c2 = __builtin_amdgcn_mfma_f32_16x16x32_bf16(hf, ks2 ? a2_1 : a2_0, c2, 0, 0, 0);
    }
    int hl = hg * 16 + lg * 4;
    int hbase = hc * 128 + hl;
    f32x4 ncv = *(const f32x4*)(ncrow + hbase);
    f32x4 qv  = *(const f32x4*)(&q2nL[hl]);
    *(f32x4*)(orow + hbase)          = ncv;
    *(f32x4*)(orow + HH + hbase)     = c2;
    *(f32x4*)(orow + 2 * HH + hbase) = ncv * c2;
    *(f32x4*)(orow + 2304 + hbase)   = ncv * qv;
  }
}

extern "C" void kernel_launch(void* const* d_in, const int* in_sizes, int n_in,
                              void* d_out, int out_size, void* d_ws, size_t ws_size,
                              hipStream_t stream) {
  (void)in_sizes; (void)n_in; (void)out_size; (void)ws_size;
  const float* nc = (const float*)d_in[0];
  const float* qc = (const float*)d_in[1];
  const float* w  = (const float*)d_in[3];
  float* out = (float*)d_out;
  char* ws = (char*)d_ws;
  unsigned short* qwB = (unsigned short*)(ws);                 // 3,145,728 B (pre-swizzled)
  unsigned short* qcT = (unsigned short*)(ws + 3145728);       // 3,145,728 B (pre-swizzled)
  float* sq_part = (float*)(ws + 6291456);                     // 49,152 B
  float* partial = (float*)(ws + 6340608);                     // 1,572,864 B
  float* mtse    = (float*)(ws + 7913472);                     // 4 KB
  unsigned short* probs = (unsigned short*)(ws + 7917568);     // 4,194,304 B

  k_prep<<<192, 256, 0, stream>>>(qc, w, qwB, qcT, sq_part);
  k_sim<<<512, 256, 0, stream>>>(nc, qwB, sq_part, partial, mtse, probs);
  k_out<<<3072, 256, 0, stream>>>(nc, qcT, probs, partial, mtse, out);
}